// Round 1
// baseline (14585.045 us; speedup 1.0000x reference)
//
#include <hip/hip_runtime.h>
#include <hip/hip_bf16.h>

// Problem constants
// N=8, CIN=256, CINT=192, COUT=128, K=3, L=512, H=W=128, OH=OW=256, IMG=3

// Workspace layout (floats unless noted)
#define WS_S_UP      0        // 8*256
#define WS_ISIG_UP   2048     // 8*192
#define WS_S_CONV    3584     // 8*192
#define WS_ISIG_CONV 5120     // 8*128
#define WS_S_RGB     6144     // 8*128
#define WS_H_BYTES   32768    // bf16 h buffer [8,192,256,256] starts here (201.3 MB)

// ---------------------------------------------------------------------------
// Kernel 1: styles + inverse demod sigmas
// ---------------------------------------------------------------------------
__global__ __launch_bounds__(256) void style_kernel(
    const float* __restrict__ v,
    const float* __restrict__ sw_up, const float* __restrict__ sb_up,
    const float* __restrict__ w_up,
    const float* __restrict__ sw_conv, const float* __restrict__ sb_conv,
    const float* __restrict__ w_conv,
    const float* __restrict__ sw_rgb, const float* __restrict__ sb_rgb,
    float* __restrict__ ws)
{
    const int n = blockIdx.x;
    const int t = threadIdx.x;
    __shared__ float sup[256];
    __shared__ float sconv[192];
    const float* vp = v + n * 512;
    {
        float a = 0.f;
        const float* r = sw_up + (size_t)t * 512;
        for (int l = 0; l < 512; ++l) a = fmaf(vp[l], r[l], a);
        float s = a + sb_up[t] + 1.0f;
        sup[t] = s;
        ws[WS_S_UP + n * 256 + t] = s;
    }
    if (t < 192) {
        float a = 0.f;
        const float* r = sw_conv + (size_t)t * 512;
        for (int l = 0; l < 512; ++l) a = fmaf(vp[l], r[l], a);
        float s = a + sb_conv[t] + 1.0f;
        sconv[t] = s;
        ws[WS_S_CONV + n * 192 + t] = s;
    }
    if (t < 128) {
        float a = 0.f;
        const float* r = sw_rgb + (size_t)t * 512;
        for (int l = 0; l < 512; ++l) a = fmaf(vp[l], r[l], a);
        ws[WS_S_RGB + n * 128 + t] = a + sb_rgb[t] + 1.0f;
    }
    __syncthreads();
    if (t < 192) {  // sigma for upconv: wsq[o,i] = sum_k w_up[i,o,k]^2
        float sum = 0.f;
        for (int i = 0; i < 256; ++i) {
            const float* w = w_up + ((size_t)i * 192 + t) * 9;
            float wsq = 0.f;
            #pragma unroll
            for (int k = 0; k < 9; ++k) wsq = fmaf(w[k], w[k], wsq);
            sum = fmaf(sup[i] * sup[i], wsq, sum);
        }
        ws[WS_ISIG_UP + n * 192 + t] = 1.0f / sqrtf(sum + 1e-8f);
    }
    if (t < 128) {  // sigma for conv: wsq[o,i] = sum_k w_conv[o,i,k]^2
        float sum = 0.f;
        for (int i = 0; i < 192; ++i) {
            const float* w = w_conv + ((size_t)t * 192 + i) * 9;
            float wsq = 0.f;
            #pragma unroll
            for (int k = 0; k < 9; ++k) wsq = fmaf(w[k], w[k], wsq);
            sum = fmaf(sconv[i] * sconv[i], wsq, sum);
        }
        ws[WS_ISIG_CONV + n * 128 + t] = 1.0f / sqrtf(sum + 1e-8f);
    }
}

// ---------------------------------------------------------------------------
// Kernel 2: modulated transposed conv (k=3,s=2,p=1,op=1) + demod + noise + act
// h[n,o,oy,ox] = sum_i sum_{iy,ix} xs[n,i,iy,ix] * w_up[i,o, oy+1-2iy, ox+1-2ix]
// Even oy: single tap (iy=oy/2, ky=1). Odd oy: (iy=oy/2, ky=2) + (iy=oy/2+1, ky=0).
// Each wave owns one output parity -> tap count & weight indices wave-uniform.
// ---------------------------------------------------------------------------
__global__ __launch_bounds__(256) void upconv_kernel(
    const float* __restrict__ x, const float* __restrict__ w_up,
    const float* __restrict__ b_up, const float* __restrict__ noise1,
    const float* __restrict__ ns1p, const float* __restrict__ ws,
    __hip_bfloat16* __restrict__ h)
{
    const int bx = blockIdx.x;          // ox tile (16 px)
    const int by = blockIdx.y;          // oy tile (16 px)
    const int bz = blockIdx.z;          // n * 12 + o-group
    const int n  = bz / 12;
    const int O0 = (bz - n * 12) * 16;
    const int tid  = threadIdx.x;
    const int wv   = __builtin_amdgcn_readfirstlane(tid >> 6);  // wave id -> SGPR
    const int py   = wv >> 1, px = wv & 1;                      // parity (uniform)
    const int lane = tid & 63;
    const int my   = lane >> 3, mx = lane & 7;                  // 8x8 sub-pixel grid

    __shared__ float ssh[256];
    __shared__ float xs[8][9][12];

    for (int i = tid; i < 256; i += 256) ssh[i] = ws[WS_S_UP + n * 256 + i];

    const int IY0 = by * 8, IX0 = bx * 8;
    float acc[16];
    #pragma unroll
    for (int o = 0; o < 16; ++o) acc[o] = 0.f;

    const int kyA = py ? 2 : 1;
    const int kxA = px ? 2 : 1;
    const int kAA = kyA * 3 + kxA;   // (yA,xA)
    const int kAB = kyA * 3;         // (yA, kx=0)  [px waves]
    const int kBA = kxA;             // (ky=0, xA)  [py waves]

    for (int i0 = 0; i0 < 256; i0 += 8) {
        __syncthreads();
        for (int idx = tid; idx < 8 * 81; idx += 256) {
            int ci = idx / 81;
            int r  = idx - ci * 81;
            int ry = r / 9, rx = r - ry * 9;
            int iy = IY0 + ry, ix = IX0 + rx;
            float val = 0.f;
            if (iy < 128 && ix < 128)
                val = x[(((size_t)n * 256 + (i0 + ci)) * 128 + iy) * 128 + ix] * ssh[i0 + ci];
            xs[ci][ry][rx] = val;
        }
        __syncthreads();
        #pragma unroll
        for (int ci = 0; ci < 8; ++ci) {
            const int i = i0 + ci;
            const float t00 = xs[ci][my][mx];
            const float t01 = px ? xs[ci][my][mx + 1] : 0.f;
            const float t10 = py ? xs[ci][my + 1][mx] : 0.f;
            const float t11 = (px & py) ? xs[ci][my + 1][mx + 1] : 0.f;
            const float* wb = w_up + ((size_t)i * 192 + O0) * 9;
            #pragma unroll
            for (int o = 0; o < 16; ++o) {
                const float* w = wb + o * 9;   // wave-uniform -> scalar loads
                float a = acc[o];
                a = fmaf(t00, w[kAA], a);
                if (px) a = fmaf(t01, w[kAB], a);
                if (py) a = fmaf(t10, w[kBA], a);
                if (px & py) a = fmaf(t11, w[0], a);
                acc[o] = a;
            }
        }
    }

    const int oy = by * 16 + 2 * my + py;
    const int ox = bx * 16 + 2 * mx + px;
    const float nz = ns1p[0] * noise1[(size_t)n * 65536 + oy * 256 + ox];
    const float* isig = ws + WS_ISIG_UP + n * 192 + O0;
    const size_t obase = (((size_t)n * 192 + O0) * 256 + oy) * 256 + ox;
    #pragma unroll
    for (int o = 0; o < 16; ++o) {
        float val = fmaf(acc[o], isig[o], b_up[O0 + o]) + nz;
        val = val > 0.f ? val : 0.2f * val;
        h[obase + (size_t)o * 65536] = __float2bfloat16(val);
    }
}

// ---------------------------------------------------------------------------
// Kernel 3: modulated 3x3 conv (192->128) + demod + noise + act -> h2 (d_out)
// ---------------------------------------------------------------------------
__global__ __launch_bounds__(256) void conv_kernel(
    const __hip_bfloat16* __restrict__ h, const float* __restrict__ w_conv,
    const float* __restrict__ b_conv, const float* __restrict__ noise2,
    const float* __restrict__ ns2p, const float* __restrict__ ws,
    float* __restrict__ h2)
{
    const int bx = blockIdx.x, by = blockIdx.y, bz = blockIdx.z;
    const int n  = bz >> 3;
    const int O0 = (bz & 7) * 16;
    const int tid = threadIdx.x;
    const int px = tid & 15, py = tid >> 4;
    const int OY = by * 16, OX = bx * 16;

    __shared__ float ssh[192];
    __shared__ float hs[8][18][20];

    for (int i = tid; i < 192; i += 256) ssh[i] = ws[WS_S_CONV + n * 192 + i];

    float acc[16];
    #pragma unroll
    for (int o = 0; o < 16; ++o) acc[o] = 0.f;

    for (int i0 = 0; i0 < 192; i0 += 8) {
        __syncthreads();
        for (int idx = tid; idx < 8 * 324; idx += 256) {
            int ci = idx / 324;
            int r  = idx - ci * 324;
            int ry = r / 18, rx = r - ry * 18;
            int iy = OY + ry - 1, ix = OX + rx - 1;
            float val = 0.f;
            if (iy >= 0 && iy < 256 && ix >= 0 && ix < 256)
                val = __bfloat162float(h[(((size_t)n * 192 + (i0 + ci)) * 256 + iy) * 256 + ix]) * ssh[i0 + ci];
            hs[ci][ry][rx] = val;
        }
        __syncthreads();
        #pragma unroll
        for (int ci = 0; ci < 8; ++ci) {
            const int i = i0 + ci;
            float t[9];
            #pragma unroll
            for (int dy = 0; dy < 3; ++dy)
                #pragma unroll
                for (int dx = 0; dx < 3; ++dx)
                    t[dy * 3 + dx] = hs[ci][py + dy][px + dx];
            const float* wb = w_conv + ((size_t)O0 * 192 + i) * 9;
            #pragma unroll
            for (int o = 0; o < 16; ++o) {
                const float* w = wb + (size_t)o * 192 * 9;  // uniform -> scalar loads
                float a = acc[o];
                #pragma unroll
                for (int k = 0; k < 9; ++k) a = fmaf(t[k], w[k], a);
                acc[o] = a;
            }
        }
    }
    const int oy = OY + py, ox = OX + px;
    const float nz = ns2p[0] * noise2[(size_t)n * 65536 + oy * 256 + ox];
    const float* isig = ws + WS_ISIG_CONV + n * 128 + O0;
    const size_t obase = (((size_t)n * 128 + O0) * 256 + oy) * 256 + ox;
    #pragma unroll
    for (int o = 0; o < 16; ++o) {
        float val = fmaf(acc[o], isig[o], b_conv[O0 + o]) + nz;
        val = val > 0.f ? val : 0.2f * val;
        h2[obase + (size_t)o * 65536] = val;
    }
}

// ---------------------------------------------------------------------------
// Kernel 4: to_rgb (1x1 modulated, no demod) + act + bilinear-upsampled skip
// ---------------------------------------------------------------------------
__global__ __launch_bounds__(256) void rgb_kernel(
    const float* __restrict__ h2, const float* __restrict__ w_rgb,
    const float* __restrict__ b_rgb, const float* __restrict__ y,
    const float* __restrict__ ws, float* __restrict__ yout)
{
    const int bid = blockIdx.x;
    const int n   = bid >> 8;                         // 256 blocks per image
    const int pix = ((bid & 255) << 8) + threadIdx.x; // 0..65535
    const int oy  = pix >> 8, ox = pix & 255;

    __shared__ float cw0[128], cw1[128], cw2[128];
    if (threadIdx.x < 128) {
        float s = ws[WS_S_RGB + n * 128 + threadIdx.x];
        cw0[threadIdx.x] = w_rgb[0 * 128 + threadIdx.x] * s;
        cw1[threadIdx.x] = w_rgb[1 * 128 + threadIdx.x] * s;
        cw2[threadIdx.x] = w_rgb[2 * 128 + threadIdx.x] * s;
    }
    __syncthreads();

    const float* hp = h2 + (size_t)n * 128 * 65536 + oy * 256 + ox;
    float a0 = 0.f, a1 = 0.f, a2 = 0.f;
    for (int i = 0; i < 128; ++i) {
        float hv = hp[(size_t)i * 65536];
        a0 = fmaf(hv, cw0[i], a0);
        a1 = fmaf(hv, cw1[i], a1);
        a2 = fmaf(hv, cw2[i], a2);
    }

    // half-pixel bilinear x2: even out -> 0.25*in[m-1]+0.75*in[m]; odd -> 0.75*in[m]+0.25*in[m+1]
    const int m = oy >> 1;
    int iy0, iy1; float wy0, wy1;
    if ((oy & 1) == 0) { iy0 = m > 0 ? m - 1 : 0; iy1 = m; wy0 = 0.25f; wy1 = 0.75f; }
    else               { iy0 = m; iy1 = m < 127 ? m + 1 : 127; wy0 = 0.75f; wy1 = 0.25f; }
    const int mm = ox >> 1;
    int ix0, ix1; float wx0, wx1;
    if ((ox & 1) == 0) { ix0 = mm > 0 ? mm - 1 : 0; ix1 = mm; wx0 = 0.25f; wx1 = 0.75f; }
    else               { ix0 = mm; ix1 = mm < 127 ? mm + 1 : 127; wx0 = 0.75f; wx1 = 0.25f; }

    float r[3] = { a0 + b_rgb[0], a1 + b_rgb[1], a2 + b_rgb[2] };
    #pragma unroll
    for (int c = 0; c < 3; ++c) {
        float t = r[c];
        t = t > 0.f ? t : 0.2f * t;
        const float* yp = y + ((size_t)n * 3 + c) * 128 * 128;
        float yu = wy0 * (wx0 * yp[iy0 * 128 + ix0] + wx1 * yp[iy0 * 128 + ix1])
                 + wy1 * (wx0 * yp[iy1 * 128 + ix0] + wx1 * yp[iy1 * 128 + ix1]);
        yout[(((size_t)n * 3 + c) * 256 + oy) * 256 + ox] = yu + t;
    }
}

// ---------------------------------------------------------------------------
extern "C" void kernel_launch(void* const* d_in, const int* in_sizes, int n_in,
                              void* d_out, int out_size, void* d_ws, size_t ws_size,
                              hipStream_t stream)
{
    const float* x       = (const float*)d_in[0];
    const float* v       = (const float*)d_in[1];
    const float* y       = (const float*)d_in[2];
    const float* noise1  = (const float*)d_in[3];
    const float* noise2  = (const float*)d_in[4];
    const float* w_up    = (const float*)d_in[5];
    const float* b_up    = (const float*)d_in[6];
    const float* sw_up   = (const float*)d_in[7];
    const float* sb_up   = (const float*)d_in[8];
    const float* w_conv  = (const float*)d_in[9];
    const float* b_conv  = (const float*)d_in[10];
    const float* sw_conv = (const float*)d_in[11];
    const float* sb_conv = (const float*)d_in[12];
    const float* w_rgb   = (const float*)d_in[13];
    const float* b_rgb   = (const float*)d_in[14];
    const float* sw_rgb  = (const float*)d_in[15];
    const float* sb_rgb  = (const float*)d_in[16];
    const float* ns1     = (const float*)d_in[17];
    const float* ns2     = (const float*)d_in[18];

    float* ws = (float*)d_ws;
    __hip_bfloat16* h = (__hip_bfloat16*)((char*)d_ws + WS_H_BYTES);  // needs ~201.4 MB ws
    float* h2   = (float*)d_out;                 // [8,128,256,256]
    float* yout = h2 + (size_t)67108864;         // [8,3,256,256]

    style_kernel<<<8, 256, 0, stream>>>(v, sw_up, sb_up, w_up, sw_conv, sb_conv,
                                        w_conv, sw_rgb, sb_rgb, ws);
    upconv_kernel<<<dim3(16, 16, 96), 256, 0, stream>>>(x, w_up, b_up, noise1, ns1, ws, h);
    conv_kernel<<<dim3(16, 16, 64), 256, 0, stream>>>(h, w_conv, b_conv, noise2, ns2, ws, h2);
    rgb_kernel<<<2048, 256, 0, stream>>>(h2, w_rgb, b_rgb, y, ws, yout);
}

// Round 2
// 3279.066 us; speedup vs baseline: 4.4479x; 4.4479x over previous
//
#include <hip/hip_runtime.h>

// N=8, CIN=256, CINT=192, COUT=128, K=3, L=512, H=W=128, OH=OW=256, IMG=3
// R2: both convs rewritten as bf16 MFMA GEMMs (16x16x32), m97-style staging.

using bfrag = __attribute__((ext_vector_type(8))) short;   // 8 bf16 (A/B frag)
using ffrag = __attribute__((ext_vector_type(4))) float;   // 4 f32 (C/D frag)

// ws float-index offsets (styles / inv-sigmas)
#define WS_S_UP      0        // 8*256
#define WS_ISIG_UP   2048     // 8*192
#define WS_S_CONV    3584     // 8*192
#define WS_ISIG_CONV 5120     // 8*128
#define WS_S_RGB     6144     // 8*128
// ws byte offsets (bf16 tensors)
#define WS_H_OFF     32768ull                       // ushort h[8][192][256][256]
#define H_ELEMS      (8ull*192*256*256)             // 100,663,296
#define WS_WUP_OFF   (WS_H_OFF + 2ull*H_ELEMS)      // wt_up_t[ky][kx][192 o][256 ci] bf16
#define WUP_ELEMS    (9*192*256)
#define WS_WCONV_OFF (WS_WUP_OFF + 2ull*WUP_ELEMS)  // wt_conv_t[tap][128 o][192 ci] bf16
#define WCONV_ELEMS  (9*128*192)

__device__ __forceinline__ unsigned short f2bf(float f) {
    unsigned u = __float_as_uint(f);
    return (unsigned short)((u + 0x7fffu + ((u >> 16) & 1u)) >> 16);
}
__device__ __forceinline__ float bf2f(unsigned short h) {
    return __uint_as_float(((unsigned)h) << 16);
}

// ---------------------------------------------------------------------------
// Kernel 1: styles + inverse demod sigmas (fp32, unchanged from R1)
// ---------------------------------------------------------------------------
__global__ __launch_bounds__(256) void style_kernel(
    const float* __restrict__ v,
    const float* __restrict__ sw_up, const float* __restrict__ sb_up,
    const float* __restrict__ w_up,
    const float* __restrict__ sw_conv, const float* __restrict__ sb_conv,
    const float* __restrict__ w_conv,
    const float* __restrict__ sw_rgb, const float* __restrict__ sb_rgb,
    float* __restrict__ ws)
{
    const int n = blockIdx.x;
    const int t = threadIdx.x;
    __shared__ float sup[256];
    __shared__ float sconv[192];
    const float* vp = v + n * 512;
    {
        float a = 0.f;
        const float* r = sw_up + (size_t)t * 512;
        for (int l = 0; l < 512; ++l) a = fmaf(vp[l], r[l], a);
        float s = a + sb_up[t] + 1.0f;
        sup[t] = s;
        ws[WS_S_UP + n * 256 + t] = s;
    }
    if (t < 192) {
        float a = 0.f;
        const float* r = sw_conv + (size_t)t * 512;
        for (int l = 0; l < 512; ++l) a = fmaf(vp[l], r[l], a);
        float s = a + sb_conv[t] + 1.0f;
        sconv[t] = s;
        ws[WS_S_CONV + n * 192 + t] = s;
    }
    if (t < 128) {
        float a = 0.f;
        const float* r = sw_rgb + (size_t)t * 512;
        for (int l = 0; l < 512; ++l) a = fmaf(vp[l], r[l], a);
        ws[WS_S_RGB + n * 128 + t] = a + sb_rgb[t] + 1.0f;
    }
    __syncthreads();
    if (t < 192) {
        float sum = 0.f;
        for (int i = 0; i < 256; ++i) {
            const float* w = w_up + ((size_t)i * 192 + t) * 9;
            float wsq = 0.f;
            #pragma unroll
            for (int k = 0; k < 9; ++k) wsq = fmaf(w[k], w[k], wsq);
            sum = fmaf(sup[i] * sup[i], wsq, sum);
        }
        ws[WS_ISIG_UP + n * 192 + t] = 1.0f / sqrtf(sum + 1e-8f);
    }
    if (t < 128) {
        float sum = 0.f;
        for (int i = 0; i < 192; ++i) {
            const float* w = w_conv + ((size_t)t * 192 + i) * 9;
            float wsq = 0.f;
            #pragma unroll
            for (int k = 0; k < 9; ++k) wsq = fmaf(w[k], w[k], wsq);
            sum = fmaf(sconv[i] * sconv[i], wsq, sum);
        }
        ws[WS_ISIG_CONV + n * 128 + t] = 1.0f / sqrtf(sum + 1e-8f);
    }
}

// ---------------------------------------------------------------------------
// Weight prepack: transpose to [tap][o][ci] bf16 so B staging is ci-contiguous
// ---------------------------------------------------------------------------
__global__ __launch_bounds__(256) void prepack_up(
    const float* __restrict__ w_up, unsigned short* __restrict__ out)
{
    int idx = blockIdx.x * 256 + threadIdx.x;
    if (idx >= WUP_ELEMS) return;
    int ci = idx & 255;
    int rest = idx >> 8;          // t*192 + o
    int o = rest % 192;
    int t = rest / 192;
    out[idx] = f2bf(w_up[((size_t)(ci * 192 + o)) * 9 + t]);
}

__global__ __launch_bounds__(256) void prepack_conv(
    const float* __restrict__ w_conv, unsigned short* __restrict__ out)
{
    int idx = blockIdx.x * 256 + threadIdx.x;
    if (idx >= WCONV_ELEMS) return;
    int ci = idx % 192;
    int rest = idx / 192;         // t*128 + o
    int o = rest & 127;
    int t = rest >> 7;
    out[idx] = f2bf(w_conv[((size_t)(o * 192 + ci)) * 9 + t]);
}

// ---------------------------------------------------------------------------
// Kernel 2: upconv as MFMA GEMM.  Block = (n, oy, x-parity, o-half 96).
// M=128 pixels (one x-parity of one output row), N=96 out-ch, K=32ci x taps.
// taps: rowsel rs (iy0+rs, ky = py?(rs?0:2):1), colsel cs (ix=m+cs, kx = px?(cs?0:2):1)
// ---------------------------------------------------------------------------
__global__ __launch_bounds__(256, 2) void upconv_mfma(
    const float* __restrict__ x, const unsigned short* __restrict__ wt,
    const float* __restrict__ b_up, const float* __restrict__ noise1,
    const float* __restrict__ ns1p, const float* __restrict__ ws,
    unsigned short* __restrict__ h)
{
    const int oy  = blockIdx.y;
    const int n   = blockIdx.z;
    const int px  = blockIdx.x & 1;
    const int O0  = (blockIdx.x >> 1) * 96;
    const int py  = oy & 1;
    const int iy0 = oy >> 1;
    const int rows = 1 + py;
    const int ntx  = 1 + px;
    const int ntaps = rows * ntx;

    const int tid  = threadIdx.x;
    const int wave = __builtin_amdgcn_readfirstlane(tid >> 6);
    const int lane = tid & 63;
    const int lm = lane & 15, quad = lane >> 4, k0 = quad * 8;
    const int wy = wave >> 1;   // m-half (64 px)
    const int wx = wave & 1;    // n-half (48 ch)

    __shared__ __align__(16) unsigned short As[2 * 132 * 40];  // [row][xx 0..128][ci pad40]
    __shared__ __align__(16) unsigned short Bs[4 * 96 * 40];   // [tap][o][ci pad40]
    __shared__ float sh_s[256];

    sh_s[tid] = ws[WS_S_UP + n * 256 + tid];

    ffrag acc[4][3] = {};

    for (int c0 = 0; c0 < 256; c0 += 32) {
        __syncthreads();
        // stage A: rows*32*129 elems; fold style; bf16 into [row][xx][ci]
        {
            const int tot = rows * 4128;          // 32*129
            for (int idx = tid; idx < tot; idx += 256) {
                int r = idx / 4128;
                int rem = idx - r * 4128;
                int c = rem / 129;
                int xx = rem - c * 129;
                int iy = iy0 + r;
                float val = 0.f;
                if (iy < 128 && xx < 128)
                    val = x[(((size_t)n * 256 + c0 + c) * 128 + iy) * 128 + xx] * sh_s[c0 + c];
                As[(r * 132 + xx) * 40 + c] = f2bf(val);
            }
        }
        // stage B for all taps of this class (u32 = 2 bf16)
        {
            const int tot = ntaps * 1536;         // 96*16
            for (int idx = tid; idx < tot; idx += 256) {
                int t = idx / 1536;
                int rem = idx - t * 1536;
                int o = rem >> 4;
                int c2 = rem & 15;
                int rs = (ntx == 2) ? (t >> 1) : t;
                int cs = (ntx == 2) ? (t & 1) : 0;
                int ky = py ? (rs ? 0 : 2) : 1;
                int kx = px ? (cs ? 0 : 2) : 1;
                unsigned int wv = *(const unsigned int*)&wt[
                    (((size_t)(ky * 3 + kx) * 192 + O0 + o) * 256) + c0 + 2 * c2];
                *(unsigned int*)&Bs[(t * 96 + o) * 40 + 2 * c2] = wv;
            }
        }
        __syncthreads();
        for (int t = 0; t < ntaps; ++t) {
            int rs = (ntx == 2) ? (t >> 1) : t;
            int cs = (ntx == 2) ? (t & 1) : 0;
            bfrag b[3];
            #pragma unroll
            for (int tn = 0; tn < 3; ++tn)
                b[tn] = *(const bfrag*)&Bs[(t * 96 + wx * 48 + tn * 16 + lm) * 40 + k0];
            #pragma unroll
            for (int tm = 0; tm < 4; ++tm) {
                bfrag a = *(const bfrag*)&As[(rs * 132 + wy * 64 + tm * 16 + lm + cs) * 40 + k0];
                #pragma unroll
                for (int tn = 0; tn < 3; ++tn)
                    acc[tm][tn] = __builtin_amdgcn_mfma_f32_16x16x32_bf16(a, b[tn], acc[tm][tn], 0, 0, 0);
            }
        }
    }

    // epilogue: demod + bias + noise + leaky -> bf16 h
    const float ns1 = ns1p[0];
    const float* isig = ws + WS_ISIG_UP + n * 192;
    #pragma unroll
    for (int tn = 0; tn < 3; ++tn) {
        const int o = O0 + wx * 48 + tn * 16 + lm;
        const float sg = isig[o];
        const float bb = b_up[o];
        #pragma unroll
        for (int tm = 0; tm < 4; ++tm) {
            #pragma unroll
            for (int r = 0; r < 4; ++r) {
                int m = wy * 64 + tm * 16 + quad * 4 + r;   // C/D: row=quad*4+reg, col=lane&15
                int ox = 2 * m + px;
                float val = acc[tm][tn][r] * sg + bb
                          + ns1 * noise1[((size_t)n * 256 + oy) * 256 + ox];
                val = val > 0.f ? val : 0.2f * val;
                h[(((size_t)n * 192 + o) * 256 + oy) * 256 + ox] = f2bf(val);
            }
        }
    }
}

// ---------------------------------------------------------------------------
// Kernel 3: 3x3 conv as MFMA GEMM. Block = (n, oy, x-half). M=128 px, N=128 o,
// K = 6 chunks x 9 taps. One A-stage per chunk serves all 9 taps (sliding win).
// ---------------------------------------------------------------------------
__global__ __launch_bounds__(256, 2) void conv_mfma(
    const unsigned short* __restrict__ h, const unsigned short* __restrict__ wt,
    const float* __restrict__ b_conv, const float* __restrict__ noise2,
    const float* __restrict__ ns2p, const float* __restrict__ ws,
    float* __restrict__ h2)
{
    const int oy = blockIdx.y;
    const int n  = blockIdx.z;
    const int X0 = (blockIdx.x & 1) * 128;
    const int tid  = threadIdx.x;
    const int wave = __builtin_amdgcn_readfirstlane(tid >> 6);
    const int lane = tid & 63;
    const int lm = lane & 15, quad = lane >> 4, k0 = quad * 8;
    const int wy = wave >> 1, wx = wave & 1;

    __shared__ __align__(16) unsigned short As[3 * 132 * 40];  // [dy][xx 0..129][ci pad40]
    __shared__ __align__(16) unsigned short Bs[3 * 128 * 40];  // [dx][o][ci pad40]
    __shared__ float sh_s[192];

    if (tid < 192) sh_s[tid] = ws[WS_S_CONV + n * 192 + tid];

    ffrag acc[4][4] = {};

    for (int c0 = 0; c0 < 192; c0 += 32) {
        __syncthreads();
        // stage A: 3*32*130, fold style, bf16
        for (int idx = tid; idx < 3 * 4160; idx += 256) {   // 32*130
            int r = idx / 4160;
            int rem = idx - r * 4160;
            int c = rem / 130;
            int xx = rem - c * 130;
            int iy = oy - 1 + r;
            int ix = X0 - 1 + xx;
            float val = 0.f;
            if (iy >= 0 && iy < 256 && ix >= 0 && ix < 256)
                val = bf2f(h[(((size_t)n * 192 + c0 + c) * 256 + iy) * 256 + ix]) * sh_s[c0 + c];
            As[(r * 132 + xx) * 40 + c] = f2bf(val);
        }
        for (int dy = 0; dy < 3; ++dy) {
            if (dy) __syncthreads();
            // stage B: 3 dx-taps of this dy row
            for (int idx = tid; idx < 3 * 2048; idx += 256) {  // 128*16
                int dx = idx >> 11;
                int rem = idx & 2047;
                int o = rem >> 4;
                int c2 = rem & 15;
                unsigned int wv = *(const unsigned int*)&wt[
                    (((size_t)(dy * 3 + dx) * 128 + o) * 192) + c0 + 2 * c2];
                *(unsigned int*)&Bs[(dx * 128 + o) * 40 + 2 * c2] = wv;
            }
            __syncthreads();
            #pragma unroll
            for (int dx = 0; dx < 3; ++dx) {
                bfrag b[4];
                #pragma unroll
                for (int tn = 0; tn < 4; ++tn)
                    b[tn] = *(const bfrag*)&Bs[(dx * 128 + wx * 64 + tn * 16 + lm) * 40 + k0];
                #pragma unroll
                for (int tm = 0; tm < 4; ++tm) {
                    bfrag a = *(const bfrag*)&As[(dy * 132 + wy * 64 + tm * 16 + lm + dx) * 40 + k0];
                    #pragma unroll
                    for (int tn = 0; tn < 4; ++tn)
                        acc[tm][tn] = __builtin_amdgcn_mfma_f32_16x16x32_bf16(a, b[tn], acc[tm][tn], 0, 0, 0);
                }
            }
        }
    }

    const float ns2 = ns2p[0];
    const float* isig = ws + WS_ISIG_CONV + n * 128;
    #pragma unroll
    for (int tn = 0; tn < 4; ++tn) {
        const int o = wx * 64 + tn * 16 + lm;
        const float sg = isig[o];
        const float bb = b_conv[o];
        #pragma unroll
        for (int tm = 0; tm < 4; ++tm) {
            #pragma unroll
            for (int r = 0; r < 4; ++r) {
                int ox = X0 + wy * 64 + tm * 16 + quad * 4 + r;
                float val = acc[tm][tn][r] * sg + bb
                          + ns2 * noise2[((size_t)n * 256 + oy) * 256 + ox];
                val = val > 0.f ? val : 0.2f * val;
                h2[(((size_t)n * 128 + o) * 256 + oy) * 256 + ox] = val;
            }
        }
    }
}

// ---------------------------------------------------------------------------
// Kernel 4: to_rgb (1x1 modulated, no demod) + act + bilinear skip (unchanged)
// ---------------------------------------------------------------------------
__global__ __launch_bounds__(256) void rgb_kernel(
    const float* __restrict__ h2, const float* __restrict__ w_rgb,
    const float* __restrict__ b_rgb, const float* __restrict__ y,
    const float* __restrict__ ws, float* __restrict__ yout)
{
    const int bid = blockIdx.x;
    const int n   = bid >> 8;
    const int pix = ((bid & 255) << 8) + threadIdx.x;
    const int oy  = pix >> 8, ox = pix & 255;

    __shared__ float cw0[128], cw1[128], cw2[128];
    if (threadIdx.x < 128) {
        float s = ws[WS_S_RGB + n * 128 + threadIdx.x];
        cw0[threadIdx.x] = w_rgb[0 * 128 + threadIdx.x] * s;
        cw1[threadIdx.x] = w_rgb[1 * 128 + threadIdx.x] * s;
        cw2[threadIdx.x] = w_rgb[2 * 128 + threadIdx.x] * s;
    }
    __syncthreads();

    const float* hp = h2 + (size_t)n * 128 * 65536 + oy * 256 + ox;
    float a0 = 0.f, a1 = 0.f, a2 = 0.f;
    for (int i = 0; i < 128; ++i) {
        float hv = hp[(size_t)i * 65536];
        a0 = fmaf(hv, cw0[i], a0);
        a1 = fmaf(hv, cw1[i], a1);
        a2 = fmaf(hv, cw2[i], a2);
    }

    const int m = oy >> 1;
    int iy0, iy1; float wy0, wy1;
    if ((oy & 1) == 0) { iy0 = m > 0 ? m - 1 : 0; iy1 = m; wy0 = 0.25f; wy1 = 0.75f; }
    else               { iy0 = m; iy1 = m < 127 ? m + 1 : 127; wy0 = 0.75f; wy1 = 0.25f; }
    const int mm = ox >> 1;
    int ix0, ix1; float wx0, wx1;
    if ((ox & 1) == 0) { ix0 = mm > 0 ? mm - 1 : 0; ix1 = mm; wx0 = 0.25f; wx1 = 0.75f; }
    else               { ix0 = mm; ix1 = mm < 127 ? mm + 1 : 127; wx0 = 0.75f; wx1 = 0.25f; }

    float r[3] = { a0 + b_rgb[0], a1 + b_rgb[1], a2 + b_rgb[2] };
    #pragma unroll
    for (int c = 0; c < 3; ++c) {
        float t = r[c];
        t = t > 0.f ? t : 0.2f * t;
        const float* yp = y + ((size_t)n * 3 + c) * 128 * 128;
        float yu = wy0 * (wx0 * yp[iy0 * 128 + ix0] + wx1 * yp[iy0 * 128 + ix1])
                 + wy1 * (wx0 * yp[iy1 * 128 + ix0] + wx1 * yp[iy1 * 128 + ix1]);
        yout[(((size_t)n * 3 + c) * 256 + oy) * 256 + ox] = yu + t;
    }
}

// ---------------------------------------------------------------------------
extern "C" void kernel_launch(void* const* d_in, const int* in_sizes, int n_in,
                              void* d_out, int out_size, void* d_ws, size_t ws_size,
                              hipStream_t stream)
{
    const float* x       = (const float*)d_in[0];
    const float* v       = (const float*)d_in[1];
    const float* y       = (const float*)d_in[2];
    const float* noise1  = (const float*)d_in[3];
    const float* noise2  = (const float*)d_in[4];
    const float* w_up    = (const float*)d_in[5];
    const float* b_up    = (const float*)d_in[6];
    const float* sw_up   = (const float*)d_in[7];
    const float* sb_up   = (const float*)d_in[8];
    const float* w_conv  = (const float*)d_in[9];
    const float* b_conv  = (const float*)d_in[10];
    const float* sw_conv = (const float*)d_in[11];
    const float* sb_conv = (const float*)d_in[12];
    const float* w_rgb   = (const float*)d_in[13];
    const float* b_rgb   = (const float*)d_in[14];
    const float* sw_rgb  = (const float*)d_in[15];
    const float* sb_rgb  = (const float*)d_in[16];
    const float* ns1     = (const float*)d_in[17];
    const float* ns2     = (const float*)d_in[18];

    float* ws = (float*)d_ws;
    unsigned short* h       = (unsigned short*)((char*)d_ws + WS_H_OFF);
    unsigned short* wt_up   = (unsigned short*)((char*)d_ws + WS_WUP_OFF);
    unsigned short* wt_conv = (unsigned short*)((char*)d_ws + WS_WCONV_OFF);
    float* h2   = (float*)d_out;                 // [8,128,256,256]
    float* yout = h2 + (size_t)67108864;         // [8,3,256,256]

    style_kernel<<<8, 256, 0, stream>>>(v, sw_up, sb_up, w_up, sw_conv, sb_conv,
                                        w_conv, sw_rgb, sb_rgb, ws);
    prepack_up<<<(WUP_ELEMS + 255) / 256, 256, 0, stream>>>(w_up, wt_up);
    prepack_conv<<<(WCONV_ELEMS + 255) / 256, 256, 0, stream>>>(w_conv, wt_conv);
    upconv_mfma<<<dim3(4, 256, 8), 256, 0, stream>>>(x, wt_up, b_up, noise1, ns1, ws, h);
    conv_mfma<<<dim3(2, 256, 8), 256, 0, stream>>>(h, wt_conv, b_conv, noise2, ns2, ws, h2);
    rgb_kernel<<<2048, 256, 0, stream>>>(h2, w_rgb, b_rgb, y, ws, yout);
}